// Round 1
// 302.035 us; speedup vs baseline: 1.2643x; 1.2643x over previous
//
#include <hip/hip_runtime.h>

#define SEQS_PER_WG 8
#define HID 128
#define NF 13
#define SLEN 128
#define NSEQ 2048
#define ZSTRIDE 232   // f16 elems per z row; 232*2=464B rows (16B aligned)

typedef _Float16 half8 __attribute__((ext_vector_type(8)));
typedef float floatx4 __attribute__((ext_vector_type(4)));

__device__ __forceinline__ float fast_rcp(float x) { return __builtin_amdgcn_rcpf(x); }
__device__ __forceinline__ float sigm(float x)  { return fast_rcp(1.0f + __expf(-x)); }
__device__ __forceinline__ float tanh_(float x) { return 1.0f - 2.0f * fast_rcp(1.0f + __expf(2.0f * x)); }

// 8 seqs/WG, 8 waves (512 thr), 256 WGs -> all 256 CUs, 2 waves/SIMD.
// Each wave owns 16 hidden units (all 4 gates): 4 MFMA tiles x 5 K-steps.
// Epilogue: rows 2,3 / 6,7 of the C tile are shuffled from quads 0,1 to
// quads 2,3 so every lane computes exactly 2 (seq,unit) cells.
__global__ __launch_bounds__(512, 2)
void lstm_encdec_kernel(const float* __restrict__ X,
                        const float* __restrict__ W_ih,
                        const float* __restrict__ W_hh,
                        const float* __restrict__ b_ih,
                        const float* __restrict__ b_hh,
                        const float* __restrict__ W_fc,
                        const float* __restrict__ b_fc,
                        float* __restrict__ out)
{
    // z = [h (128) | x (13, padded to 32)] per seq slot, fp16, double-buffered.
    // 16 row slots (A-operand reads rows 0..15); rows 8..15 stay zero.
    __shared__ _Float16 zbuf[2][16 * ZSTRIDE];

    const int tid  = threadIdx.x;
    const int wave = tid >> 6;            // 0..7
    const int lane = tid & 63;
    const int quad = lane >> 4;           // 0..3
    const int lcol = lane & 15;
    const bool hi  = quad >= 2;
    const int row0 = (quad & 1) * 4 + (hi ? 2 : 0);   // first of the 2 seq rows owned
    const int unit = wave * 16 + lcol;                // hidden unit 0..127
    const int seq0 = blockIdx.x * SEQS_PER_WG;

    // ---- loop-invariant B fragments: gates[s][n] = sum_k z[s][k]*W[n][k], n = g*128+unit
    half8 Bf[4][5];
    floatx4 biasv[4];
    #pragma unroll
    for (int g = 0; g < 4; ++g) {
        const int n = g * HID + unit;
        #pragma unroll
        for (int ks = 0; ks < 4; ++ks) {              // h part
            const float* p = W_hh + n * HID + ks * 32 + quad * 8;
            half8 v;
            #pragma unroll
            for (int j = 0; j < 8; ++j) v[j] = (_Float16)p[j];
            Bf[g][ks] = v;
        }
        {                                             // x part (K-step 4)
            half8 v;
            #pragma unroll
            for (int j = 0; j < 8; ++j) {
                int kk = quad * 8 + j;
                v[j] = (kk < NF) ? (_Float16)W_ih[n * NF + kk] : (_Float16)0.0f;
            }
            Bf[g][4] = v;
        }
        float b = b_ih[n] + b_hh[n];
        biasv[g] = (floatx4){b, b, b, b};             // first MFMA's C operand
    }

    // W_fc fragments (wave 0 only)
    half8 Wfcf[4];
    floatx4 bfcv = (floatx4){0.0f, 0.0f, 0.0f, 0.0f};
    if (wave == 0) {
        #pragma unroll
        for (int ks = 0; ks < 4; ++ks) {
            half8 v;
            #pragma unroll
            for (int j = 0; j < 8; ++j)
                v[j] = (lcol < NF) ? (_Float16)W_fc[lcol * HID + ks * 32 + quad * 8 + j]
                                   : (_Float16)0.0f;
            Wfcf[ks] = v;
        }
        float b = (lcol < NF) ? b_fc[lcol] : 0.0f;
        bfcv = (floatx4){b, b, b, b};
    }

    // ---- init LDS: zero both buffers, then x_0
    for (int i = tid; i < 2 * 16 * ZSTRIDE; i += 512)
        ((_Float16*)zbuf)[i] = (_Float16)0.0f;
    __syncthreads();

    const bool xact = tid < SEQS_PER_WG * NF;         // 104 threads load x
    const int  xs = tid / NF, xf = tid % NF;
    const long xbase = (long)(seq0 + xs) * SLEN * NF + xf;
    if (xact) zbuf[0][xs * ZSTRIDE + HID + xf] = (_Float16)X[xbase];
    __syncthreads();

    float creg[2] = {0.0f, 0.0f};
    float hkeep0 = 0.0f, hkeep1 = 0.0f;
    int p = 0;

    // ===================== encoder: 128 steps, 1 barrier/step =====================
    for (int t = 0; t < SLEN; ++t) {
        const int tn = (t + 1 < SLEN) ? t + 1 : SLEN - 1;
        float xpre = 0.0f;
        if (xact) xpre = X[xbase + tn * NF];

        const _Float16* zr = zbuf[p];
        _Float16* zw = zbuf[1 - p];

        half8 a[5];
        #pragma unroll
        for (int ks = 0; ks < 5; ++ks)
            a[ks] = *(const half8*)&zr[lcol * ZSTRIDE + ks * 32 + quad * 8];

        floatx4 acc[4];
        #pragma unroll
        for (int g = 0; g < 4; ++g)
            acc[g] = __builtin_amdgcn_mfma_f32_16x16x32_f16(a[0], Bf[g][0], biasv[g], 0, 0, 0);
        #pragma unroll
        for (int ks = 1; ks < 5; ++ks)
            #pragma unroll
            for (int g = 0; g < 4; ++g)
                acc[g] = __builtin_amdgcn_mfma_f32_16x16x32_f16(a[ks], Bf[g][ks], acc[g], 0, 0, 0);

        // redistribute rows 2,3 (quad0->quad2) and 6,7 (quad1->quad3)
        float gv0[4], gv1[4];
        #pragma unroll
        for (int g = 0; g < 4; ++g) {
            float s2 = __shfl_xor(acc[g][2], 32);
            float s3 = __shfl_xor(acc[g][3], 32);
            gv0[g] = hi ? s2 : acc[g][0];
            gv1[g] = hi ? s3 : acc[g][1];
        }

        {
            float c0 = sigm(gv0[1]) * creg[0] + sigm(gv0[0]) * tanh_(gv0[2]);
            creg[0] = c0;
            float h0 = sigm(gv0[3]) * tanh_(c0);
            float c1 = sigm(gv1[1]) * creg[1] + sigm(gv1[0]) * tanh_(gv1[2]);
            creg[1] = c1;
            float h1 = sigm(gv1[3]) * tanh_(c1);
            hkeep0 = h0; hkeep1 = h1;
            zw[(row0 + 0) * ZSTRIDE + unit] = (_Float16)h0;
            zw[(row0 + 1) * ZSTRIDE + unit] = (_Float16)h1;
        }
        if (xact) zw[xs * ZSTRIDE + HID + xf] = (_Float16)xpre;

        __syncthreads();
        p ^= 1;
    }

    // embeddings = h_n
    out[(long)(seq0 + row0 + 0) * HID + unit] = hkeep0;
    out[(long)(seq0 + row0 + 1) * HID + unit] = hkeep1;

    // ===================== decoder: 128 steps, 2 barriers/step =====================
    float* dec = out + (long)NSEQ * HID;
    for (int t = 0; t < SLEN; ++t) {
        const _Float16* zr = zbuf[p];
        _Float16* zw = zbuf[1 - p];

        half8 a[5];
        #pragma unroll
        for (int ks = 0; ks < 5; ++ks)
            a[ks] = *(const half8*)&zr[lcol * ZSTRIDE + ks * 32 + quad * 8];

        floatx4 acc[4];
        #pragma unroll
        for (int g = 0; g < 4; ++g)
            acc[g] = __builtin_amdgcn_mfma_f32_16x16x32_f16(a[0], Bf[g][0], biasv[g], 0, 0, 0);
        #pragma unroll
        for (int ks = 1; ks < 5; ++ks)
            #pragma unroll
            for (int g = 0; g < 4; ++g)
                acc[g] = __builtin_amdgcn_mfma_f32_16x16x32_f16(a[ks], Bf[g][ks], acc[g], 0, 0, 0);

        float gv0[4], gv1[4];
        #pragma unroll
        for (int g = 0; g < 4; ++g) {
            float s2 = __shfl_xor(acc[g][2], 32);
            float s3 = __shfl_xor(acc[g][3], 32);
            gv0[g] = hi ? s2 : acc[g][0];
            gv1[g] = hi ? s3 : acc[g][1];
        }
        {
            float c0 = sigm(gv0[1]) * creg[0] + sigm(gv0[0]) * tanh_(gv0[2]);
            creg[0] = c0;
            float h0 = sigm(gv0[3]) * tanh_(c0);
            float c1 = sigm(gv1[1]) * creg[1] + sigm(gv1[0]) * tanh_(gv1[2]);
            creg[1] = c1;
            float h1 = sigm(gv1[3]) * tanh_(c1);
            zw[(row0 + 0) * ZSTRIDE + unit] = (_Float16)h0;
            zw[(row0 + 1) * ZSTRIDE + unit] = (_Float16)h1;
        }

        __syncthreads();   // h_{t+1} complete in z[1-p]

        if (wave == 0) {
            half8 af[4];
            #pragma unroll
            for (int ks = 0; ks < 4; ++ks)
                af[ks] = *(const half8*)&zw[lcol * ZSTRIDE + ks * 32 + quad * 8];
            floatx4 o = bfcv;
            #pragma unroll
            for (int ks = 0; ks < 4; ++ks)
                o = __builtin_amdgcn_mfma_f32_16x16x32_f16(af[ks], Wfcf[ks], o, 0, 0, 0);
            if (quad < 2 && lcol < NF) {
                #pragma unroll
                for (int r = 0; r < 4; ++r) {
                    int srow = quad * 4 + r;       // seq rows 0..7
                    float v = o[r];
                    dec[(long)(seq0 + srow) * SLEN * NF + t * NF + lcol] = v;
                    zw[srow * ZSTRIDE + HID + lcol] = (_Float16)v;
                }
            }
        }

        __syncthreads();   // x slot of z[1-p] ready
        p ^= 1;
    }
}

extern "C" void kernel_launch(void* const* d_in, const int* in_sizes, int n_in,
                              void* d_out, int out_size, void* d_ws, size_t ws_size,
                              hipStream_t stream) {
    const float* X    = (const float*)d_in[0];
    const float* W_ih = (const float*)d_in[1];
    const float* W_hh = (const float*)d_in[2];
    const float* b_ih = (const float*)d_in[3];
    const float* b_hh = (const float*)d_in[4];
    const float* W_fc = (const float*)d_in[5];
    const float* b_fc = (const float*)d_in[6];
    float* out = (float*)d_out;

    lstm_encdec_kernel<<<NSEQ / SEQS_PER_WG, 512, 0, stream>>>(
        X, W_ih, W_hh, b_ih, b_hh, W_fc, b_fc, out);
}